// Round 1
// baseline (830.798 us; speedup 1.0000x reference)
//
#include <hip/hip_runtime.h>
#include <cmath>

#define NPTS  32768   // B*N
#define NB    8
#define NN    4096
#define FIN   32
#define KN    39      // neighbors kept (top-40 minus self)
#define PP    22
#define PPAD  24      // feats padded to 24 floats (96B, float4-aligned rows)
#define FOUT  48
#define FUP   76      // 32 + 22 + 22
#define WAVES 4

// ---------------- precompute: feats = x@Wf+bf (padded), coords = x@Ws+bs, sq ----
__global__ __launch_bounds__(256) void gn_pre(
    const float* __restrict__ x,
    const float* __restrict__ Wf, const float* __restrict__ bf,
    const float* __restrict__ Ws, const float* __restrict__ bs,
    float* __restrict__ coords4, float* __restrict__ sqarr, float* __restrict__ feats)
{
    int tid  = blockIdx.x * 256 + threadIdx.x;
    int p    = tid >> 5;          // point id 0..32767
    int t    = tid & 31;          // 0..31 within point
    int lane = threadIdx.x & 63;

    const float* xr = x + (size_t)p * FIN;
    bool isF = (t < PP);
    int  col = isF ? t : (t - PP);
    if (!isF && col >= 4) col = 0;          // dummy lanes 26..31
    const float* W    = isF ? Wf : Ws;
    int          ncol = isF ? PP : 4;
    float        bias = isF ? bf[col] : bs[col];

    float acc = 0.f;
    #pragma unroll
    for (int i = 0; i < FIN; ++i)
        acc = fmaf(xr[i], W[i * ncol + col], acc);
    acc += bias;

    if (isF)                       feats[(size_t)p * PPAD + t]   = acc;
    else if (t < PP + 4)           coords4[(size_t)p * 4 + (t - PP)] = acc;

    // sq = sum(coords^2), computed from lanes 22..25 of this point's half-wave
    int hb = lane & 32;
    float c0 = __shfl(acc, hb + PP + 0);
    float c1 = __shfl(acc, hb + PP + 1);
    float c2 = __shfl(acc, hb + PP + 2);
    float c3 = __shfl(acc, hb + PP + 3);
    if (t == PP + 4) {
        float sq = fmaf(c0, c0, fmaf(c1, c1, fmaf(c2, c2, c3 * c3)));
        sqarr[p] = sq;
    }
}

// ---------------- main fused kernel: one wave per query point --------------------
__global__ __launch_bounds__(256, 2) void gn_main(
    const float* __restrict__ x,
    const float* __restrict__ Wo, const float* __restrict__ bo,
    const float* __restrict__ coords4, const float* __restrict__ sqarr,
    const float* __restrict__ feats,
    float* __restrict__ out)
{
    __shared__ __align__(16) float lds[WAVES * NN];   // 64KB: per-wave d2 buffer

    const float INF = __builtin_inff();
    int wv   = threadIdx.x >> 6;
    int lane = threadIdx.x & 63;
    int q    = blockIdx.x * WAVES + wv;    // global query point 0..32767
    int b    = q >> 12;
    int n    = q & (NN - 1);
    float* d2b = lds + wv * NN;

    const float4* c4  = ((const float4*)coords4) + (size_t)b * NN;
    const float*  sqB = sqarr + (size_t)b * NN;

    float4 cq  = c4[n];
    float  sqn = sqB[n];

    // ---- phase 1: all 4096 d2 -> LDS; per-lane 8x8 hierarchical minima ----
    float gm[8];
    int   gj[8];
    #pragma unroll
    for (int g = 0; g < 8; ++g) {
        gm[g] = INF; gj[g] = 0;
        #pragma unroll
        for (int j = 0; j < 8; ++j) {
            int t = g * 8 + j;
            int m = t * 64 + lane;
            float4 cm = c4[m];
            float dot = fmaf(cq.x, cm.x, fmaf(cq.y, cm.y, fmaf(cq.z, cm.z, cq.w * cm.w)));
            float d2  = fmaf(-2.f, dot, sqn + sqB[m]);
            if (m == n) d2 = INF;            // exclude self
            d2b[m] = d2;
            if (d2 < gm[g]) { gm[g] = d2; gj[g] = j; }
        }
    }
    // per-lane overall min (value, t-index) with lowest-index tie-break
    float lv = gm[0]; int lt = gj[0];
    #pragma unroll
    for (int g = 1; g < 8; ++g) {
        float v = gm[g]; int tt = g * 8 + gj[g];
        if (v < lv || (v == lv && tt < lt)) { lv = v; lt = tt; }
    }
    __syncthreads();

    // ---- phase 2: 39 serial extractions (exact top-k semantics) ----
    float kd = 0.f; int km = 0;
    for (int it = 0; it < KN; ++it) {
        float v  = lv;
        int   mi = lt * 64 + lane;
        #pragma unroll
        for (int s = 1; s < 64; s <<= 1) {
            float ov = __shfl_xor(v, s);
            int   om = __shfl_xor(mi, s);
            if (ov < v || (ov == v && om < mi)) { v = ov; mi = om; }
        }
        if (lane == it) { kd = v; km = mi; }     // lane 'it' records it-th neighbor
        if (lane == (mi & 63)) {                 // winner updates its state
            int g = mi >> 9;                     // (mi>>6)>>3
            d2b[mi] = INF;
            float bv = INF; int bj = 0;
            int base = g * 8 * 64 + lane;
            #pragma unroll
            for (int j = 0; j < 8; ++j) {
                float dv = d2b[base + j * 64];
                if (dv < bv) { bv = dv; bj = j; }
            }
            #pragma unroll
            for (int h = 0; h < 8; ++h) if (h == g) { gm[h] = bv; gj[h] = bj; }
            lv = gm[0]; lt = gj[0];
            #pragma unroll
            for (int h = 1; h < 8; ++h) {
                float vv = gm[h]; int tt = h * 8 + gj[h];
                if (vv < lv || (vv == lv && tt < lt)) { lv = vv; lt = tt; }
            }
        }
    }
    __syncthreads();

    // ---- phase 3: weighted features -> LDS [k][24] ----
    float w = expf(-fabsf(kd * 10.f));
    const float4* fr = (const float4*)(feats + ((size_t)b * NN + km) * PPAD);
    float4 f0 = fr[0], f1 = fr[1], f2 = fr[2], f3 = fr[3], f4 = fr[4], f5 = fr[5];
    float* nfb = d2b;                               // reuse d2 region
    if (lane < KN) {
        float4* row = (float4*)(nfb + lane * PPAD);
        row[0] = make_float4(f0.x * w, f0.y * w, f0.z * w, f0.w * w);
        row[1] = make_float4(f1.x * w, f1.y * w, f1.z * w, f1.w * w);
        row[2] = make_float4(f2.x * w, f2.y * w, f2.z * w, f2.w * w);
        row[3] = make_float4(f3.x * w, f3.y * w, f3.z * w, f3.w * w);
        row[4] = make_float4(f4.x * w, f4.y * w, f4.z * w, f4.w * w);
        row[5] = make_float4(f5.x * w, f5.y * w, f5.z * w, f5.w * w);
    }
    __syncthreads();

    // ---- phase 4: max / mean reduction over 39 neighbors (lanes 0..21) ----
    float* agg = nfb + 40 * PPAD;
    if (lane < PP) {
        float mx = -INF, sm = 0.f;
        for (int k = 0; k < KN; ++k) {
            float vv = nfb[k * PPAD + lane];
            mx = fmaxf(mx, vv);
            sm += vv;
        }
        agg[lane]      = mx;
        agg[PP + lane] = sm * (1.f / (float)KN);
    }
    __syncthreads();

    // ---- phase 5: out = tanh([x | max | mean] @ Wo + bo), lanes 0..47 ----
    if (lane < FOUT) {
        const float* xr = x + (size_t)q * FIN;
        float acc = bo[lane];
        #pragma unroll
        for (int f = 0; f < FUP; ++f) {
            float u = (f < FIN) ? xr[f] : agg[f - FIN];
            acc = fmaf(u, Wo[f * FOUT + lane], acc);
        }
        out[(size_t)q * FOUT + lane] = tanhf(acc);
    }
}

extern "C" void kernel_launch(void* const* d_in, const int* in_sizes, int n_in,
                              void* d_out, int out_size, void* d_ws, size_t ws_size,
                              hipStream_t stream) {
    const float* x  = (const float*)d_in[0];
    const float* Wf = (const float*)d_in[1];
    const float* bf = (const float*)d_in[2];
    const float* Ws = (const float*)d_in[3];
    const float* bs = (const float*)d_in[4];
    const float* Wo = (const float*)d_in[5];
    const float* bo = (const float*)d_in[6];
    float* outp = (float*)d_out;

    float* ws      = (float*)d_ws;
    float* coords4 = ws;                         // 32768*4   = 131072 floats
    float* sqarr   = ws + 131072;                // 32768 floats
    float* feats   = ws + 131072 + 32768;        // 32768*24  = 786432 floats
    // total ws use: ~3.7 MB

    gn_pre<<<NPTS * 32 / 256, 256, 0, stream>>>(x, Wf, bf, Ws, bs, coords4, sqarr, feats);
    gn_main<<<NPTS / WAVES, 256, 0, stream>>>(x, Wo, bo, coords4, sqarr, feats, outp);
}

// Round 2
// 544.130 us; speedup vs baseline: 1.5268x; 1.5268x over previous
//
#include <hip/hip_runtime.h>
#include <cmath>

#define NN    4096
#define FIN   32
#define KSEL  39      // neighbors kept (top-40 minus self)
#define PP    22
#define PPAD  24
#define FOUT  48
#define WPB   2       // waves per block

#define WSYNC() asm volatile("s_waitcnt lgkmcnt(0)" ::: "memory")

__device__ __forceinline__ unsigned keyof(float d2) {
    unsigned u = __float_as_uint(d2);
    return ((int)u < 0) ? ~u : (u | 0x80000000u);   // monotonic total order
}

// ---------------- precompute: feats = x@Wf+bf (padded to 24), coords = x@Ws+bs ----
__global__ __launch_bounds__(256) void gn_pre(
    const float* __restrict__ x,
    const float* __restrict__ Wf, const float* __restrict__ bf,
    const float* __restrict__ Ws, const float* __restrict__ bs,
    float* __restrict__ coords4, float* __restrict__ feats)
{
    int tid = blockIdx.x * 256 + threadIdx.x;
    int p   = tid >> 5;          // point id
    int t   = tid & 31;

    const float* xr = x + (size_t)p * FIN;
    bool isF = (t < PP);
    int  col = isF ? t : (t - PP);
    bool wrC = (!isF) && (col < 4);
    if (!isF && col >= 4) col = 0;
    const float* W    = isF ? Wf : Ws;
    int          ncol = isF ? PP : 4;
    float        bias = isF ? bf[col] : bs[col];

    float acc = 0.f;
    #pragma unroll
    for (int i = 0; i < FIN; ++i)
        acc = fmaf(xr[i], W[i * ncol + col], acc);
    acc += bias;

    if (isF)      feats[(size_t)p * PPAD + t]        = acc;
    else if (wrC) coords4[(size_t)p * 4 + (t - PP)]  = acc;
}

// wave-cooperative radix scan: find digit bin D s.t. cum count reaches R; R -= cum_before
__device__ __forceinline__ int radix_scan(const unsigned* hist, int lane, int& R) {
    int h0 = (int)hist[lane * 4 + 0];
    int h1 = (int)hist[lane * 4 + 1];
    int h2 = (int)hist[lane * 4 + 2];
    int h3 = (int)hist[lane * 4 + 3];
    int i0 = h0, i1 = i0 + h1, i2 = i1 + h2, i3 = i2 + h3;
    int sc = i3;
    #pragma unroll
    for (int s = 1; s < 64; s <<= 1) {
        int o = __shfl_up(sc, (unsigned)s);
        if (lane >= s) sc += o;
    }
    int base = sc - i3;               // exclusive prefix over 4-bin chunks
    int j, excl;
    if      (base + i0 >= R) { j = 0; excl = base;      }
    else if (base + i1 >= R) { j = 1; excl = base + i0; }
    else if (base + i2 >= R) { j = 2; excl = base + i1; }
    else if (base + i3 >= R) { j = 3; excl = base + i2; }
    else                     { j = 4; excl = 0;         }
    unsigned pack = (j < 4) ? (((unsigned)(lane * 4 + j) << 16) | (unsigned)excl)
                            : 0xFFFFFFFFu;
    #pragma unroll
    for (int s = 1; s < 64; s <<= 1) {
        unsigned o = (unsigned)__shfl_xor((int)pack, s);
        pack = pack < o ? pack : o;
    }
    R -= (int)(pack & 0xFFFFu);
    return (int)(pack >> 16);
}

// ---------------- main: one wave per query, radix-select top-39 ------------------
__global__ __launch_bounds__(WPB * 64) void gn_main(
    const float* __restrict__ x,
    const float* __restrict__ Wo, const float* __restrict__ bo,
    const float* __restrict__ coords4, const float* __restrict__ feats,
    float* __restrict__ out)
{
    __shared__ unsigned keybuf_s[WPB * 2048];   // 16-bit keys, 2 per u32
    __shared__ unsigned hist_s[WPB * 256];      // per-wave 256-bin hist / sel / agg

    const float NEGINF = -__builtin_inff();
    const int wv   = threadIdx.x >> 6;
    const int lane = threadIdx.x & 63;
    const int q    = blockIdx.x * WPB + wv;
    const int b    = q >> 12;
    const int n    = q & (NN - 1);
    unsigned* keybuf = keybuf_s + wv * 2048;
    unsigned* hist   = hist_s   + wv * 256;

    const float4* c4 = ((const float4*)coords4) + (size_t)b * NN;
    float4 cq = c4[n];
    float  sqn = fmaf(cq.x, cq.x, fmaf(cq.y, cq.y, fmaf(cq.z, cq.z, cq.w * cq.w)));
    float4 m2 = make_float4(-2.f * cq.x, -2.f * cq.y, -2.f * cq.z, -2.f * cq.w);

    auto d2of = [&](float4 cm) -> float {
        float a = sqn;
        a = fmaf(cm.x, cm.x + m2.x, a);
        a = fmaf(cm.y, cm.y + m2.y, a);
        a = fmaf(cm.z, cm.z + m2.z, a);
        a = fmaf(cm.w, cm.w + m2.w, a);
        return a;
    };

    // ---- pass 1: compute keys, store 16-bit prefixes, hist on bits[31:24] ----
    hist[lane] = 0; hist[lane + 64] = 0; hist[lane + 128] = 0; hist[lane + 192] = 0;
    WSYNC();
    for (int t = 0; t < 32; ++t) {
        int i  = t * 64 + lane;
        int m0 = i * 2;
        float4 ca = c4[m0];
        float4 cb = c4[m0 + 1];
        unsigned ka = (m0     == n) ? 0xFFFFFFFFu : keyof(d2of(ca));
        unsigned kb = (m0 + 1 == n) ? 0xFFFFFFFFu : keyof(d2of(cb));
        keybuf[i] = (ka >> 16) | (kb & 0xFFFF0000u);
        atomicAdd(&hist[ka >> 24], 1u);
        atomicAdd(&hist[kb >> 24], 1u);
    }
    WSYNC();
    int R = KSEL;
    int D1 = radix_scan(hist, lane, R);

    // ---- pass 2: bits[23:16] among top-byte==D1 (from LDS keys) ----
    WSYNC();
    hist[lane] = 0; hist[lane + 64] = 0; hist[lane + 128] = 0; hist[lane + 192] = 0;
    WSYNC();
    for (int t = 0; t < 32; ++t) {
        unsigned w  = keybuf[t * 64 + lane];
        unsigned kA = w & 0xFFFFu, kB = w >> 16;
        if ((int)(kA >> 8) == D1) atomicAdd(&hist[kA & 0xFFu], 1u);
        if ((int)(kB >> 8) == D1) atomicAdd(&hist[kB & 0xFFu], 1u);
    }
    WSYNC();
    int D2 = radix_scan(hist, lane, R);
    const unsigned T16 = ((unsigned)D1 << 8) | (unsigned)D2;

    // ---- pass 3: bits[15:8] among key16==T16 (exact recompute, rare) ----
    WSYNC();
    hist[lane] = 0; hist[lane + 64] = 0; hist[lane + 128] = 0; hist[lane + 192] = 0;
    WSYNC();
    for (int t = 0; t < 32; ++t) {
        int i = t * 64 + lane;
        unsigned w  = keybuf[i];
        unsigned kA = w & 0xFFFFu, kB = w >> 16;
        if (kA == T16) {
            unsigned kf = keyof(d2of(c4[2 * i]));
            atomicAdd(&hist[(kf >> 8) & 0xFFu], 1u);
        }
        if (kB == T16) {
            unsigned kf = keyof(d2of(c4[2 * i + 1]));
            atomicAdd(&hist[(kf >> 8) & 0xFFu], 1u);
        }
    }
    WSYNC();
    int D3 = radix_scan(hist, lane, R);

    // ---- pass 4: bits[7:0] ----
    WSYNC();
    hist[lane] = 0; hist[lane + 64] = 0; hist[lane + 128] = 0; hist[lane + 192] = 0;
    WSYNC();
    for (int t = 0; t < 32; ++t) {
        int i = t * 64 + lane;
        unsigned w  = keybuf[i];
        unsigned kA = w & 0xFFFFu, kB = w >> 16;
        if (kA == T16) {
            unsigned kf = keyof(d2of(c4[2 * i]));
            if ((int)((kf >> 8) & 0xFFu) == D3) atomicAdd(&hist[kf & 0xFFu], 1u);
        }
        if (kB == T16) {
            unsigned kf = keyof(d2of(c4[2 * i + 1]));
            if ((int)((kf >> 8) & 0xFFu) == D3) atomicAdd(&hist[kf & 0xFFu], 1u);
        }
    }
    WSYNC();
    int D4 = radix_scan(hist, lane, R);
    const int t_need = R;                                   // ties at T32 to take
    const unsigned T32 = (T16 << 16) | ((unsigned)D3 << 8) | (unsigned)D4;

    // ---- collect: exact set, index-ordered tie-break, ballot compaction ----
    WSYNC();
    unsigned* sel = hist;                                   // reuse (64 entries)
    const unsigned long long lt = (1ull << lane) - 1ull;
    int nsel = 0, ntie = 0;
    for (int t = 0; t < 64; ++t) {
        int m = t * 64 + lane;
        unsigned w   = keybuf[m >> 1];
        unsigned k16 = (m & 1) ? (w >> 16) : (w & 0xFFFFu);
        bool less = k16 < T16;
        bool iseq = (k16 == T16);
        unsigned kf = 0xFFFFFFFFu;
        if (iseq) kf = keyof(d2of(c4[m]));
        bool sl    = less || (iseq && kf < T32);
        bool eqf   = iseq && (kf == T32);
        unsigned long long beq = __ballot(eqf);
        bool tk    = eqf && ((ntie + (int)__popcll(beq & lt)) < t_need);
        unsigned long long btake = __ballot(sl || tk);
        if (sl || tk) {
            int slot = nsel + (int)__popcll(btake & lt);
            sel[slot & 63] = (unsigned)m;
        }
        nsel += (int)__popcll(btake);
        ntie += (int)__popcll(beq);
    }
    WSYNC();

    // ---- weighted features -> LDS [39][24] (reuse keybuf region) ----
    float* fstage = (float*)keybuf;
    float* agg    = (float*)(hist + 64);    // 44 floats
    if (lane < KSEL) {
        int m = (int)(sel[lane] & (NN - 1));
        float d2  = d2of(c4[m]);
        float wgt = expf(-fabsf(10.f * d2));
        const float4* fr = (const float4*)(feats + ((size_t)b * NN + m) * PPAD);
        float4 f0 = fr[0], f1 = fr[1], f2 = fr[2], f3 = fr[3], f4 = fr[4], f5 = fr[5];
        float4* row = (float4*)(fstage + lane * PPAD);
        row[0] = make_float4(f0.x * wgt, f0.y * wgt, f0.z * wgt, f0.w * wgt);
        row[1] = make_float4(f1.x * wgt, f1.y * wgt, f1.z * wgt, f1.w * wgt);
        row[2] = make_float4(f2.x * wgt, f2.y * wgt, f2.z * wgt, f2.w * wgt);
        row[3] = make_float4(f3.x * wgt, f3.y * wgt, f3.z * wgt, f3.w * wgt);
        row[4] = make_float4(f4.x * wgt, f4.y * wgt, f4.z * wgt, f4.w * wgt);
        row[5] = make_float4(f5.x * wgt, f5.y * wgt, f5.z * wgt, f5.w * wgt);
    }
    WSYNC();

    // ---- max / mean over 39 neighbors (lanes 0..21) ----
    if (lane < PP) {
        float mx = NEGINF, sm = 0.f;
        for (int k = 0; k < KSEL; ++k) {
            float v = fstage[k * PPAD + lane];
            mx = fmaxf(mx, v);
            sm += v;
        }
        agg[lane]      = mx;
        agg[PP + lane] = sm * (1.f / (float)KSEL);
    }
    WSYNC();

    // ---- epilogue: out = tanh([x | max | mean] @ Wo + bo) ----
    if (lane < FOUT) {
        const float* xr = x + (size_t)q * FIN;
        float acc = bo[lane];
        #pragma unroll
        for (int f = 0; f < FIN; ++f)
            acc = fmaf(xr[f], Wo[f * FOUT + lane], acc);
        #pragma unroll
        for (int f = 0; f < 2 * PP; ++f)
            acc = fmaf(agg[f], Wo[(FIN + f) * FOUT + lane], acc);
        out[(size_t)q * FOUT + lane] = tanhf(acc);
    }
}

extern "C" void kernel_launch(void* const* d_in, const int* in_sizes, int n_in,
                              void* d_out, int out_size, void* d_ws, size_t ws_size,
                              hipStream_t stream) {
    const float* x  = (const float*)d_in[0];
    const float* Wf = (const float*)d_in[1];
    const float* bf = (const float*)d_in[2];
    const float* Ws = (const float*)d_in[3];
    const float* bs = (const float*)d_in[4];
    const float* Wo = (const float*)d_in[5];
    const float* bo = (const float*)d_in[6];
    float* outp = (float*)d_out;

    float* ws      = (float*)d_ws;
    float* coords4 = ws;                    // 32768*4  = 131072 floats
    float* feats   = ws + 131072;           // 32768*24 = 786432 floats

    gn_pre<<<(32768 * 32) / 256, 256, 0, stream>>>(x, Wf, bf, Ws, bs, coords4, feats);
    gn_main<<<32768 / WPB, WPB * 64, 0, stream>>>(x, Wo, bo, coords4, feats, outp);
}

// Round 3
// 294.529 us; speedup vs baseline: 2.8208x; 1.8475x over previous
//
#include <hip/hip_runtime.h>
#include <cmath>

#define NN    4096
#define FIN   32
#define KSEL  39      // neighbors kept (top-40 minus self)
#define PP    22
#define PPAD  24
#define FOUT  48
#define WPB   2       // waves per block
#define CAP   512     // candidate overflow cap (degenerate data -> fallback)

#define WSYNC() asm volatile("s_waitcnt lgkmcnt(0)" ::: "memory")

__device__ __forceinline__ unsigned keyof(float d2) {
    unsigned u = __float_as_uint(d2);
    return ((int)u < 0) ? ~u : (u | 0x80000000u);   // monotonic total order
}

// ---------------- precompute: feats = x@Wf+bf (padded to 24), coords = x@Ws+bs ----
__global__ __launch_bounds__(256) void gn_pre(
    const float* __restrict__ x,
    const float* __restrict__ Wf, const float* __restrict__ bf,
    const float* __restrict__ Ws, const float* __restrict__ bs,
    float* __restrict__ coords4, float* __restrict__ feats)
{
    int tid = blockIdx.x * 256 + threadIdx.x;
    int p   = tid >> 5;          // point id
    int t   = tid & 31;

    const float4* xr4 = (const float4*)(x + (size_t)p * FIN);
    float4 xv[8];
    #pragma unroll
    for (int i = 0; i < 8; ++i) xv[i] = xr4[i];

    bool isF = (t < PP);
    int  col = isF ? t : (t - PP);
    bool wrC = (!isF) && (col < 4);
    if (!isF && col >= 4) col = 0;
    const float* W    = isF ? Wf : Ws;
    int          ncol = isF ? PP : 4;
    float        bias = isF ? bf[col] : bs[col];

    float acc = 0.f;
    #pragma unroll
    for (int i = 0; i < 8; ++i) {
        acc = fmaf(xv[i].x, W[(4 * i + 0) * ncol + col], acc);
        acc = fmaf(xv[i].y, W[(4 * i + 1) * ncol + col], acc);
        acc = fmaf(xv[i].z, W[(4 * i + 2) * ncol + col], acc);
        acc = fmaf(xv[i].w, W[(4 * i + 3) * ncol + col], acc);
    }
    acc += bias;

    if (isF)      feats[(size_t)p * PPAD + t]        = acc;
    else if (wrC) coords4[(size_t)p * 4 + (t - PP)]  = acc;
}

// full 64-lane bitonic sort, unsigned keys, ascending
__device__ __forceinline__ unsigned sort64_u32(unsigned v, int lane) {
    #pragma unroll
    for (int k = 2; k <= 64; k <<= 1) {
        #pragma unroll
        for (int j = k >> 1; j >= 1; j >>= 1) {
            unsigned ov = (unsigned)__shfl_xor((int)v, j);
            bool keepMin = (((lane & j) == 0) == ((lane & k) == 0));
            bool less = ov < v;
            v = (less == keepMin) ? ov : v;
        }
    }
    return v;
}

// full 64-lane bitonic sort of (float d2, int idx), ascending lexicographic
__device__ __forceinline__ void sort64_pair(float& v, int& m, int lane) {
    #pragma unroll
    for (int k = 2; k <= 64; k <<= 1) {
        #pragma unroll
        for (int j = k >> 1; j >= 1; j >>= 1) {
            float ov = __shfl_xor(v, j);
            int   om = __shfl_xor(m, j);
            bool keepMin = (((lane & j) == 0) == ((lane & k) == 0));
            bool less = (ov < v) || (ov == v && om < m);
            bool take = (less == keepMin);
            v = take ? ov : v;
            m = take ? om : m;
        }
    }
}

// merge sorted-ascending running list (Lv,Lm) with sorted-ascending chunk (cv,cm):
// keep the 64 smallest, result sorted ascending
__device__ __forceinline__ void merge64(float& Lv, int& Lm, float cv, int cm, int lane) {
    float rv = __shfl_xor(cv, 63);
    int   rm = __shfl_xor(cm, 63);
    bool less = (rv < Lv) || (rv == Lv && rm < Lm);
    if (less) { Lv = rv; Lm = rm; }
    #pragma unroll
    for (int j = 32; j >= 1; j >>= 1) {
        float ov = __shfl_xor(Lv, j);
        int   om = __shfl_xor(Lm, j);
        bool lower = ((lane & j) == 0);
        bool l2 = (ov < Lv) || (ov == Lv && om < Lm);
        bool take = (l2 == lower);
        Lv = take ? ov : Lv;
        Lm = take ? om : Lm;
    }
}

// ---------------- main: one wave per query ---------------------------------------
__global__ __launch_bounds__(WPB * 64) void gn_main(
    const float* __restrict__ x,
    const float* __restrict__ Wo, const float* __restrict__ bo,
    const float* __restrict__ coords4, const float* __restrict__ feats,
    float* __restrict__ out)
{
    __shared__ unsigned keybuf_s[WPB * 2048];   // 16-bit keys, 2 per u32 (8KB/wave)
    __shared__ unsigned sel_s[WPB * CAP];       // candidate indices (2KB/wave)

    const float INF = __builtin_inff();
    const float NEGINF = -INF;
    const int wv   = threadIdx.x >> 6;
    const int lane = threadIdx.x & 63;
    const int q    = blockIdx.x * WPB + wv;
    const int b    = q >> 12;
    const int n    = q & (NN - 1);
    unsigned* keybuf = keybuf_s + wv * 2048;
    unsigned* sel    = sel_s    + wv * CAP;

    const float4* c4 = ((const float4*)coords4) + (size_t)b * NN;
    float4 cq = c4[n];
    float  sqn = fmaf(cq.x, cq.x, fmaf(cq.y, cq.y, fmaf(cq.z, cq.z, cq.w * cq.w)));
    float4 m2 = make_float4(-2.f * cq.x, -2.f * cq.y, -2.f * cq.z, -2.f * cq.w);

    auto d2of = [&](float4 cm) -> float {
        float a = sqn;
        a = fmaf(cm.x, cm.x + m2.x, a);
        a = fmaf(cm.y, cm.y + m2.y, a);
        a = fmaf(cm.z, cm.z + m2.z, a);
        a = fmaf(cm.w, cm.w + m2.w, a);
        return a;
    };

    // ---- pass 1: 16-bit keys -> LDS, track per-lane min key ----
    unsigned kmin = 0xFFFFFFFFu;
    for (int i = 0; i < 32; ++i) {
        int w  = i * 64 + lane;
        int m0 = w * 2;
        float4 ca = c4[m0];
        float4 cb = c4[m0 + 1];
        unsigned ka = (m0     == n) ? 0xFFFFFFFFu : keyof(d2of(ca));
        unsigned kb = (m0 + 1 == n) ? 0xFFFFFFFFu : keyof(d2of(cb));
        keybuf[w] = (ka >> 16) | (kb & 0xFFFF0000u);
        kmin = min(kmin, min(ka, kb));
    }
    WSYNC();

    // ---- bound: UB = 39th smallest of the 64 lane minima ----
    unsigned smin = sort64_u32(kmin, lane);
    unsigned UB16 = ((unsigned)__shfl((int)smin, KSEL - 1)) >> 16;

    // ---- compact candidates {k16 <= UB16} (exact superset of top-39) ----
    const unsigned long long lt = (1ull << lane) - 1ull;
    int C = 0;
    for (int i = 0; i < 32; ++i) {
        int w0 = i * 64 + lane;
        unsigned w  = keybuf[w0];
        unsigned kA = w & 0xFFFFu, kB = w >> 16;
        int m0 = w0 * 2;
        bool pA = (kA <= UB16);
        bool pB = (kB <= UB16);
        unsigned long long bA = __ballot(pA);
        unsigned long long bB = __ballot(pB);
        int cA = (int)__popcll(bA);
        if (pA) { int s = C + (int)__popcll(bA & lt);      if (s < CAP) sel[s] = (unsigned)m0; }
        if (pB) { int s = C + cA + (int)__popcll(bB & lt); if (s < CAP) sel[s] = (unsigned)(m0 + 1); }
        C += cA + (int)__popcll(bB);
    }
    WSYNC();

    // ---- exact top-39 by (d2, idx): bitonic sort chunks + merge ----
    float Lv = INF; int Lm = 0x7FFFFFFF;
    if (C <= CAP) {
        int nch = (C + 63) >> 6;
        for (int c = 0; c < nch; ++c) {
            int s = c * 64 + lane;
            float v; int m;
            if (s < C) { m = (int)sel[s]; v = d2of(c4[m]); }
            else       { m = 0x7FFFFFFF; v = INF; }
            sort64_pair(v, m, lane);
            if (c == 0) { Lv = v; Lm = m; }
            else        merge64(Lv, Lm, v, m, lane);
        }
    } else {
        // degenerate fallback: exact streaming top-64 over all 4096
        for (int c = 0; c < 64; ++c) {
            int m = c * 64 + lane;
            float v = (m == n) ? INF : d2of(c4[m]);
            sort64_pair(v, m, lane);
            if (c == 0) { Lv = v; Lm = m; }
            else        merge64(Lv, Lm, v, m, lane);
        }
    }
    // lanes 0..38 now hold the 39 nearest (d2 ascending, index tie-break)

    // ---- weighted features -> LDS [39][24] (reuse keybuf region) ----
    float* fstage = (float*)keybuf;
    float* agg    = (float*)sel;    // 44 floats (sel no longer needed)
    if (lane < KSEL) {
        int m = Lm;
        float wgt = expf(-fabsf(10.f * Lv));
        const float4* fr = (const float4*)(feats + ((size_t)b * NN + m) * PPAD);
        float4 f0 = fr[0], f1 = fr[1], f2 = fr[2], f3 = fr[3], f4 = fr[4], f5 = fr[5];
        float4* row = (float4*)(fstage + lane * PPAD);
        row[0] = make_float4(f0.x * wgt, f0.y * wgt, f0.z * wgt, f0.w * wgt);
        row[1] = make_float4(f1.x * wgt, f1.y * wgt, f1.z * wgt, f1.w * wgt);
        row[2] = make_float4(f2.x * wgt, f2.y * wgt, f2.z * wgt, f2.w * wgt);
        row[3] = make_float4(f3.x * wgt, f3.y * wgt, f3.z * wgt, f3.w * wgt);
        row[4] = make_float4(f4.x * wgt, f4.y * wgt, f4.z * wgt, f4.w * wgt);
        row[5] = make_float4(f5.x * wgt, f5.y * wgt, f5.z * wgt, f5.w * wgt);
    }
    WSYNC();

    // ---- max / mean over 39 neighbors (lanes 0..21) ----
    if (lane < PP) {
        float mx = NEGINF, sm = 0.f;
        for (int k = 0; k < KSEL; ++k) {
            float v = fstage[k * PPAD + lane];
            mx = fmaxf(mx, v);
            sm += v;
        }
        agg[lane]      = mx;
        agg[PP + lane] = sm * (1.f / (float)KSEL);
    }
    WSYNC();

    // ---- epilogue: out = tanh([x | max | mean] @ Wo + bo) ----
    if (lane < FOUT) {
        const float* xr = x + (size_t)q * FIN;
        float acc = bo[lane];
        #pragma unroll
        for (int f = 0; f < FIN; ++f)
            acc = fmaf(xr[f], Wo[f * FOUT + lane], acc);
        #pragma unroll
        for (int f = 0; f < 2 * PP; ++f)
            acc = fmaf(agg[f], Wo[(FIN + f) * FOUT + lane], acc);
        out[(size_t)q * FOUT + lane] = tanhf(acc);
    }
}

extern "C" void kernel_launch(void* const* d_in, const int* in_sizes, int n_in,
                              void* d_out, int out_size, void* d_ws, size_t ws_size,
                              hipStream_t stream) {
    const float* x  = (const float*)d_in[0];
    const float* Wf = (const float*)d_in[1];
    const float* bf = (const float*)d_in[2];
    const float* Ws = (const float*)d_in[3];
    const float* bs = (const float*)d_in[4];
    const float* Wo = (const float*)d_in[5];
    const float* bo = (const float*)d_in[6];
    float* outp = (float*)d_out;

    float* ws      = (float*)d_ws;
    float* coords4 = ws;                    // 32768*4  = 131072 floats
    float* feats   = ws + 131072;           // 32768*24 = 786432 floats

    gn_pre<<<(32768 * 32) / 256, 256, 0, stream>>>(x, Wf, bf, Ws, bs, coords4, feats);
    gn_main<<<32768 / WPB, WPB * 64, 0, stream>>>(x, Wo, bo, coords4, feats, outp);
}

// Round 4
// 265.121 us; speedup vs baseline: 3.1337x; 1.1109x over previous
//
#include <hip/hip_runtime.h>
#include <cmath>

#define NN    4096
#define FIN   32
#define KSEL  39      // neighbors kept (top-40 minus self)
#define PP    22
#define PPAD  24
#define FOUT  48
#define WPB   2       // waves per block
#define CAP   256     // candidate overflow cap (degenerate data -> fallback)

#define WSYNC() asm volatile("s_waitcnt lgkmcnt(0)" ::: "memory")

// ---------------- precompute: feats = x@Wf+bf (padded to 24), coords = x@Ws+bs ----
__global__ __launch_bounds__(256) void gn_pre(
    const float* __restrict__ x,
    const float* __restrict__ Wf, const float* __restrict__ bf,
    const float* __restrict__ Ws, const float* __restrict__ bs,
    float* __restrict__ coords4, float* __restrict__ feats)
{
    int tid = blockIdx.x * 256 + threadIdx.x;
    int p   = tid >> 5;          // point id
    int t   = tid & 31;

    const float4* xr4 = (const float4*)(x + (size_t)p * FIN);
    float4 xv[8];
    #pragma unroll
    for (int i = 0; i < 8; ++i) xv[i] = xr4[i];

    bool isF = (t < PP);
    int  col = isF ? t : (t - PP);
    bool wrC = (!isF) && (col < 4);
    if (!isF && col >= 4) col = 0;
    const float* W    = isF ? Wf : Ws;
    int          ncol = isF ? PP : 4;
    float        bias = isF ? bf[col] : bs[col];

    float acc = 0.f;
    #pragma unroll
    for (int i = 0; i < 8; ++i) {
        acc = fmaf(xv[i].x, W[(4 * i + 0) * ncol + col], acc);
        acc = fmaf(xv[i].y, W[(4 * i + 1) * ncol + col], acc);
        acc = fmaf(xv[i].z, W[(4 * i + 2) * ncol + col], acc);
        acc = fmaf(xv[i].w, W[(4 * i + 3) * ncol + col], acc);
    }
    acc += bias;

    if (isF)      feats[(size_t)p * PPAD + t]        = acc;
    else if (wrC) coords4[(size_t)p * 4 + (t - PP)]  = acc;
}

// full 64-lane bitonic sort, float keys, ascending
__device__ __forceinline__ float sortf64(float v, int lane) {
    #pragma unroll
    for (int k = 2; k <= 64; k <<= 1) {
        #pragma unroll
        for (int j = k >> 1; j >= 1; j >>= 1) {
            float ov = __shfl_xor(v, j);
            bool keepMin = (((lane & j) == 0) == ((lane & k) == 0));
            bool less = ov < v;
            v = (less == keepMin) ? ov : v;
        }
    }
    return v;
}

// full 64-lane bitonic sort of (float d2, int idx), ascending lexicographic
__device__ __forceinline__ void sort64_pair(float& v, int& m, int lane) {
    #pragma unroll
    for (int k = 2; k <= 64; k <<= 1) {
        #pragma unroll
        for (int j = k >> 1; j >= 1; j >>= 1) {
            float ov = __shfl_xor(v, j);
            int   om = __shfl_xor(m, j);
            bool keepMin = (((lane & j) == 0) == ((lane & k) == 0));
            bool less = (ov < v) || (ov == v && om < m);
            bool take = (less == keepMin);
            v = take ? ov : v;
            m = take ? om : m;
        }
    }
}

// merge sorted-ascending running list (Lv,Lm) with sorted-ascending chunk (cv,cm):
// keep the 64 smallest, result sorted ascending
__device__ __forceinline__ void merge64(float& Lv, int& Lm, float cv, int cm, int lane) {
    float rv = __shfl_xor(cv, 63);
    int   rm = __shfl_xor(cm, 63);
    bool less = (rv < Lv) || (rv == Lv && rm < Lm);
    if (less) { Lv = rv; Lm = rm; }
    #pragma unroll
    for (int j = 32; j >= 1; j >>= 1) {
        float ov = __shfl_xor(Lv, j);
        int   om = __shfl_xor(Lm, j);
        bool lower = ((lane & j) == 0);
        bool l2 = (ov < Lv) || (ov == Lv && om < Lm);
        bool take = (l2 == lower);
        Lv = take ? ov : Lv;
        Lm = take ? om : Lm;
    }
}

// ---------------- main: one wave per query ---------------------------------------
__global__ __launch_bounds__(WPB * 64, 6) void gn_main(
    const float* __restrict__ x,
    const float* __restrict__ Wo, const float* __restrict__ bo,
    const float* __restrict__ coords4, const float* __restrict__ feats,
    float* __restrict__ out)
{
    __shared__ unsigned short sel_s[WPB * CAP];          // 512 B/wave
    __shared__ float fstage_s[WPB * KSEL * PPAD];        // 3744 B/wave
    __shared__ float agg_s[WPB * 48];                    // 192 B/wave

    const float INF = __builtin_inff();
    const float NEGINF = -INF;
    const int wv   = threadIdx.x >> 6;
    const int lane = threadIdx.x & 63;
    const int q    = blockIdx.x * WPB + wv;
    const int b    = q >> 12;
    const int n    = q & (NN - 1);
    unsigned short* sel    = sel_s + wv * CAP;
    float*          fstage = fstage_s + wv * (KSEL * PPAD);
    float*          agg    = agg_s + wv * 48;

    const float4* c4 = ((const float4*)coords4) + (size_t)b * NN;
    float4 cq = c4[n];
    float  sqn = fmaf(cq.x, cq.x, fmaf(cq.y, cq.y, fmaf(cq.z, cq.z, cq.w * cq.w)));
    float4 m2 = make_float4(-2.f * cq.x, -2.f * cq.y, -2.f * cq.z, -2.f * cq.w);

    auto d2of = [&](float4 cm) -> float {
        float a = sqn;
        a = fmaf(cm.x, cm.x + m2.x, a);
        a = fmaf(cm.y, cm.y + m2.y, a);
        a = fmaf(cm.z, cm.z + m2.z, a);
        a = fmaf(cm.w, cm.w + m2.w, a);
        return a;
    };

    // ---- pass 1: per-lane running min over 64 elems (self INCLUDED) ----
    float kmin = INF;
    #pragma unroll 2
    for (int i = 0; i < 16; ++i) {
        int mA = i * 256 + lane;
        float dA = d2of(c4[mA]);
        float dB = d2of(c4[mA + 64]);
        float dC = d2of(c4[mA + 128]);
        float dD = d2of(c4[mA + 192]);
        kmin = fminf(kmin, fminf(fminf(dA, dB), fminf(dC, dD)));
    }

    // ---- bound: UB = 40th smallest of the 64 lane minima (covers self) ----
    float smin = sortf64(kmin, lane);
    float UB = __shfl(smin, KSEL);     // index 39 = 40th smallest

    // ---- compact candidates {d2 <= UB, m != n} (exact superset of top-39) ----
    const unsigned long long lt = (1ull << lane) - 1ull;
    int C = 0;
    for (int i = 0; i < 16; ++i) {
        int mA = i * 256 + lane;
        float dA = d2of(c4[mA]);
        float dB = d2of(c4[mA + 64]);
        float dC = d2of(c4[mA + 128]);
        float dD = d2of(c4[mA + 192]);
        bool pA = (dA <= UB) && (mA       != n);
        bool pB = (dB <= UB) && (mA + 64  != n);
        bool pC = (dC <= UB) && (mA + 128 != n);
        bool pD = (dD <= UB) && (mA + 192 != n);
        unsigned long long bA = __ballot(pA); int cA = (int)__popcll(bA);
        unsigned long long bB = __ballot(pB); int cB = (int)__popcll(bB);
        unsigned long long bC = __ballot(pC); int cC = (int)__popcll(bC);
        unsigned long long bD = __ballot(pD); int cD = (int)__popcll(bD);
        if (pA) { int s = C +                (int)__popcll(bA & lt); if (s < CAP) sel[s] = (unsigned short)mA; }
        if (pB) { int s = C + cA +           (int)__popcll(bB & lt); if (s < CAP) sel[s] = (unsigned short)(mA + 64); }
        if (pC) { int s = C + cA + cB +      (int)__popcll(bC & lt); if (s < CAP) sel[s] = (unsigned short)(mA + 128); }
        if (pD) { int s = C + cA + cB + cC + (int)__popcll(bD & lt); if (s < CAP) sel[s] = (unsigned short)(mA + 192); }
        C += cA + cB + cC + cD;
    }
    WSYNC();

    // ---- exact top-39 by (d2, idx): bitonic sort chunks + merge ----
    float Lv = INF; int Lm = 0x7FFFFFFF;
    if (C <= CAP) {
        int nch = (C + 63) >> 6;
        for (int c = 0; c < nch; ++c) {
            int s = c * 64 + lane;
            float v; int m;
            if (s < C) { m = (int)sel[s]; v = d2of(c4[m]); }
            else       { m = 0x7FFFFFFF; v = INF; }
            sort64_pair(v, m, lane);
            if (c == 0) { Lv = v; Lm = m; }
            else        merge64(Lv, Lm, v, m, lane);
        }
    } else {
        // degenerate fallback: exact streaming top-64 over all 4096
        for (int c = 0; c < 64; ++c) {
            int m = c * 64 + lane;
            float v = (m == n) ? INF : d2of(c4[m]);
            sort64_pair(v, m, lane);
            if (c == 0) { Lv = v; Lm = m; }
            else        merge64(Lv, Lm, v, m, lane);
        }
    }
    // lanes 0..38 now hold the 39 nearest (d2 ascending, index tie-break)

    // ---- weighted features -> LDS [39][24] ----
    if (lane < KSEL) {
        float wgt = __expf(-fabsf(10.f * Lv));
        const float4* fr = (const float4*)(feats + ((size_t)b * NN + Lm) * PPAD);
        float4 f0 = fr[0], f1 = fr[1], f2 = fr[2], f3 = fr[3], f4 = fr[4], f5 = fr[5];
        float4* row = (float4*)(fstage + lane * PPAD);
        row[0] = make_float4(f0.x * wgt, f0.y * wgt, f0.z * wgt, f0.w * wgt);
        row[1] = make_float4(f1.x * wgt, f1.y * wgt, f1.z * wgt, f1.w * wgt);
        row[2] = make_float4(f2.x * wgt, f2.y * wgt, f2.z * wgt, f2.w * wgt);
        row[3] = make_float4(f3.x * wgt, f3.y * wgt, f3.z * wgt, f3.w * wgt);
        row[4] = make_float4(f4.x * wgt, f4.y * wgt, f4.z * wgt, f4.w * wgt);
        row[5] = make_float4(f5.x * wgt, f5.y * wgt, f5.z * wgt, f5.w * wgt);
    }
    WSYNC();

    // ---- max / mean over 39 neighbors (lanes 0..21) ----
    if (lane < PP) {
        float mx = NEGINF, sm = 0.f;
        for (int k = 0; k < KSEL; ++k) {
            float v = fstage[k * PPAD + lane];
            mx = fmaxf(mx, v);
            sm += v;
        }
        agg[lane]      = mx;
        agg[PP + lane] = sm * (1.f / (float)KSEL);
    }
    WSYNC();

    // ---- epilogue: out = tanh([x | max | mean] @ Wo + bo), fast tanh ----
    if (lane < FOUT) {
        const float* xr = x + (size_t)q * FIN;
        float acc = bo[lane];
        #pragma unroll
        for (int f = 0; f < FIN; ++f)
            acc = fmaf(xr[f], Wo[f * FOUT + lane], acc);
        #pragma unroll
        for (int f = 0; f < 2 * PP; ++f)
            acc = fmaf(agg[f], Wo[(FIN + f) * FOUT + lane], acc);
        // tanh(x) = 1 - 2/(e^{2x}+1)
        float e = __expf(2.f * acc);
        float r = __builtin_amdgcn_rcpf(e + 1.f);
        out[(size_t)q * FOUT + lane] = fmaf(-2.f, r, 1.f);
    }
}

extern "C" void kernel_launch(void* const* d_in, const int* in_sizes, int n_in,
                              void* d_out, int out_size, void* d_ws, size_t ws_size,
                              hipStream_t stream) {
    const float* x  = (const float*)d_in[0];
    const float* Wf = (const float*)d_in[1];
    const float* bf = (const float*)d_in[2];
    const float* Ws = (const float*)d_in[3];
    const float* bs = (const float*)d_in[4];
    const float* Wo = (const float*)d_in[5];
    const float* bo = (const float*)d_in[6];
    float* outp = (float*)d_out;

    float* ws      = (float*)d_ws;
    float* coords4 = ws;                    // 32768*4  = 131072 floats
    float* feats   = ws + 131072;           // 32768*24 = 786432 floats

    gn_pre<<<(32768 * 32) / 256, 256, 0, stream>>>(x, Wf, bf, Ws, bs, coords4, feats);
    gn_main<<<32768 / WPB, WPB * 64, 0, stream>>>(x, Wo, bo, coords4, feats, outp);
}